// Round 7
// baseline (2390.184 us; speedup 1.0000x reference)
//
#include <hip/hip_runtime.h>
#include <math.h>

#define LYRS 6
#define BATCH 16
#define DIM 1024
#define NH 16
#define HDIM 64
#define FFNDIM 4096
#define VOCAB 32000
#define NCACHE 512
#define SRCLEN 512
#define SCALE 0.125f
#define EMB_SCALE 32.0f
#define NB 256
#define BD (BATCH * DIM)
#define BF (BATCH * FFNDIM)
#define BV (BATCH * VOCAB)

__device__ __forceinline__ float wave_reduce_sum(float v){
#pragma unroll
  for (int off = 32; off; off >>= 1) v += __shfl_xor(v, off, 64);
  return v;
}
__device__ __forceinline__ float wave_reduce_max(float v){
#pragma unroll
  for (int off = 32; off; off >>= 1) v = fmaxf(v, __shfl_xor(v, off, 64));
  return v;
}
__device__ __forceinline__ float4 silu4(float4 v){
  v.x = v.x / (1.f + __expf(-v.x));
  v.y = v.y / (1.f + __expf(-v.y));
  v.z = v.z / (1.f + __expf(-v.z));
  v.w = v.w / (1.f + __expf(-v.w));
  return v;
}

// ---- coherent (agent-scope, L2-bypass) accessors for cross-phase buffers ----
__device__ __forceinline__ float gld(const float* p){
  return __hip_atomic_load(p, __ATOMIC_RELAXED, __HIP_MEMORY_SCOPE_AGENT);
}
__device__ __forceinline__ void gst(float* p, float v){
  __hip_atomic_store(p, v, __ATOMIC_RELAXED, __HIP_MEMORY_SCOPE_AGENT);
}
__device__ __forceinline__ float4 gld4(const float* p){
  unsigned long long a = __hip_atomic_load((const unsigned long long*)p,
      __ATOMIC_RELAXED, __HIP_MEMORY_SCOPE_AGENT);
  unsigned long long b = __hip_atomic_load((const unsigned long long*)(p + 2),
      __ATOMIC_RELAXED, __HIP_MEMORY_SCOPE_AGENT);
  float4 r;
  r.x = __uint_as_float((unsigned)a); r.y = __uint_as_float((unsigned)(a >> 32));
  r.z = __uint_as_float((unsigned)b); r.w = __uint_as_float((unsigned)(b >> 32));
  return r;
}
__device__ __forceinline__ void gst4(float* p, float4 v){
  unsigned long long a = (unsigned long long)__float_as_uint(v.x) |
                         ((unsigned long long)__float_as_uint(v.y) << 32);
  unsigned long long b = (unsigned long long)__float_as_uint(v.z) |
                         ((unsigned long long)__float_as_uint(v.w) << 32);
  __hip_atomic_store((unsigned long long*)p, a, __ATOMIC_RELAXED,
                     __HIP_MEMORY_SCOPE_AGENT);
  __hip_atomic_store((unsigned long long*)(p + 2), b, __ATOMIC_RELAXED,
                     __HIP_MEMORY_SCOPE_AGENT);
}

union SMem {
  float As[16 * 512];
  struct { float qs[64], ks[64], vs[64], sc[516], red1[4], red2[4], o4[4][64]; } at;
  struct { float qsT[64][16]; float Ps[4][16][64]; } gm;
  struct { float pT[512][16]; float Ps[4][16][64]; } cx;
  struct { float r1[4], r2[4]; } ln;
};

// Two-level counter barrier. 16 leaves (128B apart) + 1 root. tid0:
// fetch_add leaf; 16th arriver of this generation bumps root; spin on root.
// __syncthreads() before the add drains each wave's sc1 stores to the
// coherence point, so root-visibility implies data-visibility.
__device__ __forceinline__ void grid_barrier(int* bar, int g){
  __syncthreads();
  if (threadIdx.x == 0){
    const int l = blockIdx.x & 15;
    int old = __hip_atomic_fetch_add(&bar[l * 32], 1, __ATOMIC_RELAXED,
                                     __HIP_MEMORY_SCOPE_AGENT);
    if (old == g * 16 - 1)
      __hip_atomic_fetch_add(&bar[512], 1, __ATOMIC_RELAXED,
                             __HIP_MEMORY_SCOPE_AGENT);
    while (__hip_atomic_load(&bar[512], __ATOMIC_RELAXED,
                             __HIP_MEMORY_SCOPE_AGENT) < g * 16)
      ;
  }
  __syncthreads();
}

// m-split GEMV tile: C_z[m][n0+lane] = sum_{k in [k0,k0+KPB)} A[m][k]*W[n][k].
// A (ws buffer) staged via coherent loads; W (weights/enc) via cached loads.
template<int KPB, int NZ, bool SILU>
__device__ __forceinline__ void gemv_core(float* As,
    const float* __restrict__ Asrc, int a_rs, int pz,
    const float* __restrict__ abias,
    const float* __restrict__ W, int w_rs,
    float* __restrict__ Cz, int c_rs, int n0, int k0){
  const int tid = threadIdx.x;
  {
    const int m = tid >> 4, q0 = (tid & 15) * 4;
#pragma unroll
    for (int qq = 0; qq < KPB / 64; ++qq){
      const int q = q0 + qq * 64;
      const int gk = k0 + q;
      float4 v;
      if (NZ == 0){
        v = gld4(Asrc + (size_t)m * a_rs + gk);
      } else {
        if (abias) v = *(const float4*)(abias + gk);
        else v = make_float4(0.f, 0.f, 0.f, 0.f);
#pragma unroll
        for (int z = 0; z < NZ; ++z){
          float4 pv = gld4(Asrc + (size_t)z * pz + (size_t)m * a_rs + gk);
          v.x += pv.x; v.y += pv.y; v.z += pv.z; v.w += pv.w;
        }
      }
      if (SILU) v = silu4(v);
      *(float4*)(As + m * KPB + q) = v;
    }
  }
  __syncthreads();
  const int lane = tid & 63;
  const int m0 = (tid >> 6) * 4;
  const float* Wrow = W + (size_t)(n0 + lane) * w_rs + k0;
  float acc0 = 0.f, acc1 = 0.f, acc2 = 0.f, acc3 = 0.f;
  constexpr int CHUNKS = KPB / 64;
  float4 wb[2][16];
#pragma unroll
  for (int cc = 0; cc < 16; ++cc) wb[0][cc] = *(const float4*)(Wrow + cc * 4);
#pragma unroll
  for (int ch = 0; ch < CHUNKS; ++ch){
    const int cur = ch & 1;
    if (ch + 1 < CHUNKS){
#pragma unroll
      for (int cc = 0; cc < 16; ++cc)
        wb[cur ^ 1][cc] = *(const float4*)(Wrow + (ch + 1) * 64 + cc * 4);
    }
#pragma unroll
    for (int cc = 0; cc < 16; ++cc){
      float4 wv = wb[cur][cc];
      const int q = ch * 64 + cc * 4;
      float4 a0 = *(const float4*)(As + (m0 + 0) * KPB + q);
      float4 a1 = *(const float4*)(As + (m0 + 1) * KPB + q);
      float4 a2 = *(const float4*)(As + (m0 + 2) * KPB + q);
      float4 a3 = *(const float4*)(As + (m0 + 3) * KPB + q);
      acc0 = fmaf(wv.x, a0.x, acc0); acc0 = fmaf(wv.y, a0.y, acc0);
      acc0 = fmaf(wv.z, a0.z, acc0); acc0 = fmaf(wv.w, a0.w, acc0);
      acc1 = fmaf(wv.x, a1.x, acc1); acc1 = fmaf(wv.y, a1.y, acc1);
      acc1 = fmaf(wv.z, a1.z, acc1); acc1 = fmaf(wv.w, a1.w, acc1);
      acc2 = fmaf(wv.x, a2.x, acc2); acc2 = fmaf(wv.y, a2.y, acc2);
      acc2 = fmaf(wv.z, a2.z, acc2); acc2 = fmaf(wv.w, a2.w, acc2);
      acc3 = fmaf(wv.x, a3.x, acc3); acc3 = fmaf(wv.y, a3.y, acc3);
      acc3 = fmaf(wv.z, a3.z, acc3); acc3 = fmaf(wv.w, a3.w, acc3);
    }
  }
  gst(&Cz[(size_t)(m0 + 0) * c_rs + n0 + lane], acc0);
  gst(&Cz[(size_t)(m0 + 1) * c_rs + n0 + lane], acc1);
  gst(&Cz[(size_t)(m0 + 2) * c_rs + n0 + lane], acc2);
  gst(&Cz[(size_t)(m0 + 3) * c_rs + n0 + lane], acc3);
  __syncthreads();
}

// Self-attention tile (b,h). Folds 16 QKV k-split partials (+bias), writes
// new k/v (plain stores: host-read only), attends over 513 keys.
__device__ __forceinline__ void attn_tile(SMem& sm, int bh,
    const float* __restrict__ Pqkv,
    const float* __restrict__ qb_, const float* __restrict__ kb_,
    const float* __restrict__ vb_,
    const float* __restrict__ pk, const float* __restrict__ pv,
    float* __restrict__ satt, float* __restrict__ out_k,
    float* __restrict__ out_v){
  const int b = bh >> 4, h = bh & 15;
  const int tid = threadIdx.x, w = tid >> 6, lane = tid & 63;
  const int hd = h * HDIM + lane;
  if (w < 3){
    const float* Pz = Pqkv + (size_t)w * (16 * BD);
    const float* bias = (w == 0) ? qb_ : ((w == 1) ? kb_ : vb_);
    float v = bias[hd];
#pragma unroll
    for (int z = 0; z < 16; ++z) v += gld(Pz + (size_t)z * BD + b * DIM + hd);
    if (w == 0) sm.at.qs[lane] = v * SCALE;
    else if (w == 1){ sm.at.ks[lane] = v; out_k[b * DIM + hd] = v; }
    else { sm.at.vs[lane] = v; out_v[b * DIM + hd] = v; }
  }
  __syncthreads();
  const int jj = lane >> 4, c = lane & 15;
  const int rbase = w * 16 + jj * 4;
  float4 q4 = *(const float4*)(&sm.at.qs[c * 4]);
  const float* kbase = pk + (size_t)b * NCACHE * DIM + h * HDIM + c * 4;
  {
    const float* kp0 = kbase + (size_t)rbase * DIM;
    float4 c0 = *(const float4*)(kp0);
    float4 c1 = *(const float4*)(kp0 + DIM);
    float4 c2 = *(const float4*)(kp0 + 2 * DIM);
    float4 c3 = *(const float4*)(kp0 + 3 * DIM);
    for (int it = 0; it < 8; ++it){
      float4 n0, n1, n2, n3;
      if (it < 7){
        const float* kp = kbase + (size_t)((it + 1) * 64 + rbase) * DIM;
        n0 = *(const float4*)(kp);
        n1 = *(const float4*)(kp + DIM);
        n2 = *(const float4*)(kp + 2 * DIM);
        n3 = *(const float4*)(kp + 3 * DIM);
      }
      const int j = it * 64 + rbase;
      float r0 = q4.x * c0.x; r0 = fmaf(q4.y, c0.y, r0);
      r0 = fmaf(q4.z, c0.z, r0); r0 = fmaf(q4.w, c0.w, r0);
      float r1 = q4.x * c1.x; r1 = fmaf(q4.y, c1.y, r1);
      r1 = fmaf(q4.z, c1.z, r1); r1 = fmaf(q4.w, c1.w, r1);
      float r2 = q4.x * c2.x; r2 = fmaf(q4.y, c2.y, r2);
      r2 = fmaf(q4.z, c2.z, r2); r2 = fmaf(q4.w, c2.w, r2);
      float r3 = q4.x * c3.x; r3 = fmaf(q4.y, c3.y, r3);
      r3 = fmaf(q4.z, c3.z, r3); r3 = fmaf(q4.w, c3.w, r3);
#pragma unroll
      for (int o = 1; o <= 8; o <<= 1){
        r0 += __shfl_xor(r0, o, 64); r1 += __shfl_xor(r1, o, 64);
        r2 += __shfl_xor(r2, o, 64); r3 += __shfl_xor(r3, o, 64);
      }
      if (c == 0){
        sm.at.sc[j] = r0; sm.at.sc[j + 1] = r1;
        sm.at.sc[j + 2] = r2; sm.at.sc[j + 3] = r3;
      }
      if (it < 7){ c0 = n0; c1 = n1; c2 = n2; c3 = n3; }
    }
  }
  if (w == 3){
    float4 k4 = *(const float4*)(&sm.at.ks[c * 4]);
    float r = q4.x * k4.x; r = fmaf(q4.y, k4.y, r);
    r = fmaf(q4.z, k4.z, r); r = fmaf(q4.w, k4.w, r);
#pragma unroll
    for (int o = 1; o <= 8; o <<= 1) r += __shfl_xor(r, o, 64);
    if (lane == 0) sm.at.sc[512] = r;
  }
  __syncthreads();
  float mx = -1e30f;
  for (int j = tid; j < 513; j += 256) mx = fmaxf(mx, sm.at.sc[j]);
  mx = wave_reduce_max(mx);
  if (lane == 0) sm.at.red1[w] = mx;
  __syncthreads();
  float bm = fmaxf(fmaxf(sm.at.red1[0], sm.at.red1[1]),
                   fmaxf(sm.at.red1[2], sm.at.red1[3]));
  float ls = 0.f;
  for (int j = tid; j < 513; j += 256){
    float e = __expf(sm.at.sc[j] - bm);
    sm.at.sc[j] = e; ls += e;
  }
  ls = wave_reduce_sum(ls);
  if (lane == 0) sm.at.red2[w] = ls;
  __syncthreads();
  float inv = 1.f / (sm.at.red2[0] + sm.at.red2[1] + sm.at.red2[2] + sm.at.red2[3]);
  const float* vbase = pv + (size_t)b * NCACHE * DIM + h * HDIM + c * 4;
  float4 acc = make_float4(0.f, 0.f, 0.f, 0.f);
  {
    const float* vp0 = vbase + (size_t)rbase * DIM;
    float4 c0 = *(const float4*)(vp0);
    float4 c1 = *(const float4*)(vp0 + DIM);
    float4 c2 = *(const float4*)(vp0 + 2 * DIM);
    float4 c3 = *(const float4*)(vp0 + 3 * DIM);
    for (int it = 0; it < 8; ++it){
      float4 n0, n1, n2, n3;
      if (it < 7){
        const float* vp = vbase + (size_t)((it + 1) * 64 + rbase) * DIM;
        n0 = *(const float4*)(vp);
        n1 = *(const float4*)(vp + DIM);
        n2 = *(const float4*)(vp + 2 * DIM);
        n3 = *(const float4*)(vp + 3 * DIM);
      }
      const int j = it * 64 + rbase;
      float p0 = sm.at.sc[j], p1 = sm.at.sc[j + 1];
      float p2 = sm.at.sc[j + 2], p3 = sm.at.sc[j + 3];
      acc.x = fmaf(p0, c0.x, acc.x); acc.y = fmaf(p0, c0.y, acc.y);
      acc.z = fmaf(p0, c0.z, acc.z); acc.w = fmaf(p0, c0.w, acc.w);
      acc.x = fmaf(p1, c1.x, acc.x); acc.y = fmaf(p1, c1.y, acc.y);
      acc.z = fmaf(p1, c1.z, acc.z); acc.w = fmaf(p1, c1.w, acc.w);
      acc.x = fmaf(p2, c2.x, acc.x); acc.y = fmaf(p2, c2.y, acc.y);
      acc.z = fmaf(p2, c2.z, acc.z); acc.w = fmaf(p2, c2.w, acc.w);
      acc.x = fmaf(p3, c3.x, acc.x); acc.y = fmaf(p3, c3.y, acc.y);
      acc.z = fmaf(p3, c3.z, acc.z); acc.w = fmaf(p3, c3.w, acc.w);
      if (it < 7){ c0 = n0; c1 = n1; c2 = n2; c3 = n3; }
    }
  }
  acc.x += __shfl_xor(acc.x, 16, 64); acc.x += __shfl_xor(acc.x, 32, 64);
  acc.y += __shfl_xor(acc.y, 16, 64); acc.y += __shfl_xor(acc.y, 32, 64);
  acc.z += __shfl_xor(acc.z, 16, 64); acc.z += __shfl_xor(acc.z, 32, 64);
  acc.w += __shfl_xor(acc.w, 16, 64); acc.w += __shfl_xor(acc.w, 32, 64);
  if (jj == 0){
    sm.at.o4[w][c * 4 + 0] = acc.x; sm.at.o4[w][c * 4 + 1] = acc.y;
    sm.at.o4[w][c * 4 + 2] = acc.z; sm.at.o4[w][c * 4 + 3] = acc.w;
  }
  __syncthreads();
  if (tid < 64){
    float s = sm.at.o4[0][tid] + sm.at.o4[1][tid] + sm.at.o4[2][tid] +
              sm.at.o4[3][tid] + sm.at.sc[512] * sm.at.vs[tid];
    gst(&satt[b * DIM + h * HDIM + tid], s * inv);
  }
  __syncthreads();
}

// h[b] = LayerNorm(res[b] + sum_z P[z][b] + obias) * w + bln
template<int NZ>
__device__ __forceinline__ void ln_tile(SMem& sm, int b,
    const float* __restrict__ res, const float* __restrict__ P, int zs,
    const float* __restrict__ obias, const float* __restrict__ w,
    const float* __restrict__ bln, float* __restrict__ outh){
  const int tid = threadIdx.x, wave = tid >> 6, lane = tid & 63;
  float4 rv = gld4(res + (size_t)b * DIM + tid * 4);
  float4 ob = ((const float4*)obias)[tid];
  float v0 = rv.x + ob.x, v1 = rv.y + ob.y, v2 = rv.z + ob.z, v3 = rv.w + ob.w;
#pragma unroll
  for (int z = 0; z < NZ; ++z){
    float4 pz = gld4(P + (size_t)z * zs + (size_t)b * DIM + tid * 4);
    v0 += pz.x; v1 += pz.y; v2 += pz.z; v3 += pz.w;
  }
  float s = v0 + v1 + v2 + v3;
  float sq = v0 * v0 + v1 * v1 + v2 * v2 + v3 * v3;
  s = wave_reduce_sum(s); sq = wave_reduce_sum(sq);
  if (lane == 0){ sm.ln.r1[wave] = s; sm.ln.r2[wave] = sq; }
  __syncthreads();
  float ts = sm.ln.r1[0] + sm.ln.r1[1] + sm.ln.r1[2] + sm.ln.r1[3];
  float tq = sm.ln.r2[0] + sm.ln.r2[1] + sm.ln.r2[2] + sm.ln.r2[3];
  float mean = ts * (1.f / DIM);
  float var = tq * (1.f / DIM) - mean * mean;
  float rstd = rsqrtf(var + 1e-5f);
  float4 wv = ((const float4*)w)[tid], bv = ((const float4*)bln)[tid];
  float4 o;
  o.x = (v0 - mean) * rstd * wv.x + bv.x;
  o.y = (v1 - mean) * rstd * wv.y + bv.y;
  o.z = (v2 - mean) * rstd * wv.z + bv.z;
  o.w = (v3 - mean) * rstd * wv.w + bv.w;
  gst4(outh + (size_t)b * DIM + tid * 4, o);
  __syncthreads();
}

// g[b][h][c0+lane] = sum_d qv[b][h*64+d]*kw[h*64+d][c], qv=(sum16 Pcq+caqb)*SCALE
__device__ __forceinline__ void gmat2_tile(SMem& sm, int tile,
    const float* __restrict__ Pcq, const float* __restrict__ caqb,
    const float* __restrict__ kw, float* __restrict__ gbuf){
  const int h = tile >> 4, c0 = (tile & 15) * 64;
  const int tid = threadIdx.x, lane = tid & 63, wave = tid >> 6;
  {
    const int b = tid >> 4, q0 = (tid & 15) * 4;
    float4 v = *(const float4*)(caqb + h * HDIM + q0);
#pragma unroll
    for (int z = 0; z < 16; ++z){
      float4 pv = gld4(Pcq + (size_t)z * BD + (size_t)b * DIM + h * HDIM + q0);
      v.x += pv.x; v.y += pv.y; v.z += pv.z; v.w += pv.w;
    }
    sm.gm.qsT[q0 + 0][b] = v.x * SCALE; sm.gm.qsT[q0 + 1][b] = v.y * SCALE;
    sm.gm.qsT[q0 + 2][b] = v.z * SCALE; sm.gm.qsT[q0 + 3][b] = v.w * SCALE;
  }
  __syncthreads();
  float wv[16];
#pragma unroll
  for (int dd = 0; dd < 16; ++dd)
    wv[dd] = kw[(size_t)(h * HDIM + wave * 16 + dd) * DIM + c0 + lane];
  float acc[16];
#pragma unroll
  for (int m = 0; m < 16; ++m) acc[m] = 0.f;
#pragma unroll
  for (int dd = 0; dd < 16; ++dd){
    const int d = wave * 16 + dd;
    float4 a0 = *(const float4*)(&sm.gm.qsT[d][0]);
    float4 a1 = *(const float4*)(&sm.gm.qsT[d][4]);
    float4 a2 = *(const float4*)(&sm.gm.qsT[d][8]);
    float4 a3 = *(const float4*)(&sm.gm.qsT[d][12]);
    float wd = wv[dd];
    acc[0] = fmaf(wd, a0.x, acc[0]);  acc[1] = fmaf(wd, a0.y, acc[1]);
    acc[2] = fmaf(wd, a0.z, acc[2]);  acc[3] = fmaf(wd, a0.w, acc[3]);
    acc[4] = fmaf(wd, a1.x, acc[4]);  acc[5] = fmaf(wd, a1.y, acc[5]);
    acc[6] = fmaf(wd, a1.z, acc[6]);  acc[7] = fmaf(wd, a1.w, acc[7]);
    acc[8] = fmaf(wd, a2.x, acc[8]);  acc[9] = fmaf(wd, a2.y, acc[9]);
    acc[10] = fmaf(wd, a2.z, acc[10]); acc[11] = fmaf(wd, a2.w, acc[11]);
    acc[12] = fmaf(wd, a3.x, acc[12]); acc[13] = fmaf(wd, a3.y, acc[13]);
    acc[14] = fmaf(wd, a3.z, acc[14]); acc[15] = fmaf(wd, a3.w, acc[15]);
  }
#pragma unroll
  for (int m = 0; m < 16; ++m) sm.gm.Ps[wave][m][lane] = acc[m];
  __syncthreads();
  const int nl = tid & 63, mg = (tid >> 6) * 4;
#pragma unroll
  for (int mm = 0; mm < 4; ++mm){
    int m = mg + mm;
    float r = sm.gm.Ps[0][m][nl] + sm.gm.Ps[1][m][nl] +
              sm.gm.Ps[2][m][nl] + sm.gm.Ps[3][m][nl];
    gst(&gbuf[((size_t)m * NH + h) * DIM + c0 + nl], r);
  }
  __syncthreads();
}

// ctx tile with INLINE softmax: stages S = sum of 2 score slabs, computes
// per-(h) row softmax within each 16-lane group, then ctx = p . enc.
__device__ __forceinline__ void ctx_sm_tile(SMem& sm, int tile,
    const float* __restrict__ s2b, const float* __restrict__ enc,
    float* __restrict__ ctx){
  const int b = tile >> 4, c0 = (tile & 15) * 64;
  const int tid = threadIdx.x, lane = tid & 63, wave = tid >> 6;
  {
    const int h = tid >> 4, jp = (tid & 15) * 4;
    const size_t row = ((size_t)b * NH + h) * SRCLEN;
    float4 val[8];
    float vmax = -1e30f;
#pragma unroll
    for (int t = 0; t < 8; ++t){
      const int j = jp + t * 64;
      float4 v = gld4(s2b + row + j);
      float4 v2 = gld4(s2b + (size_t)(BATCH * NH * SRCLEN) + row + j);
      v.x += v2.x; v.y += v2.y; v.z += v2.z; v.w += v2.w;
      val[t] = v;
      vmax = fmaxf(vmax, fmaxf(fmaxf(v.x, v.y), fmaxf(v.z, v.w)));
    }
#pragma unroll
    for (int o = 1; o <= 8; o <<= 1) vmax = fmaxf(vmax, __shfl_xor(vmax, o, 64));
    float lsum = 0.f;
#pragma unroll
    for (int t = 0; t < 8; ++t){
      val[t].x = __expf(val[t].x - vmax); val[t].y = __expf(val[t].y - vmax);
      val[t].z = __expf(val[t].z - vmax); val[t].w = __expf(val[t].w - vmax);
      lsum += val[t].x + val[t].y + val[t].z + val[t].w;
    }
#pragma unroll
    for (int o = 1; o <= 8; o <<= 1) lsum += __shfl_xor(lsum, o, 64);
    float inv = 1.f / lsum;
#pragma unroll
    for (int t = 0; t < 8; ++t){
      const int j = jp + t * 64;
      sm.cx.pT[j + 0][h] = val[t].x * inv; sm.cx.pT[j + 1][h] = val[t].y * inv;
      sm.cx.pT[j + 2][h] = val[t].z * inv; sm.cx.pT[j + 3][h] = val[t].w * inv;
    }
  }
  __syncthreads();
  const float* ep = enc + (size_t)b * SRCLEN * DIM + c0 + lane;
  const int jb = wave * 128;
  float acc[16];
#pragma unroll
  for (int m = 0; m < 16; ++m) acc[m] = 0.f;
  float cur[8], nxt[8];
#pragma unroll
  for (int i = 0; i < 8; ++i) cur[i] = ep[(size_t)(jb + i) * DIM];
#pragma unroll
  for (int t = 0; t < 16; ++t){
    if (t < 15){
#pragma unroll
      for (int i = 0; i < 8; ++i)
        nxt[i] = ep[(size_t)(jb + (t + 1) * 8 + i) * DIM];
    }
#pragma unroll
    for (int i = 0; i < 8; ++i){
      const int j = jb + t * 8 + i;
      float4 p0 = *(const float4*)(&sm.cx.pT[j][0]);
      float4 p1 = *(const float4*)(&sm.cx.pT[j][4]);
      float4 p2 = *(const float4*)(&sm.cx.pT[j][8]);
      float4 p3 = *(const float4*)(&sm.cx.pT[j][12]);
      float ev = cur[i];
      acc[0] = fmaf(p0.x, ev, acc[0]);  acc[1] = fmaf(p0.y, ev, acc[1]);
      acc[2] = fmaf(p0.z, ev, acc[2]);  acc[3] = fmaf(p0.w, ev, acc[3]);
      acc[4] = fmaf(p1.x, ev, acc[4]);  acc[5] = fmaf(p1.y, ev, acc[5]);
      acc[6] = fmaf(p1.z, ev, acc[6]);  acc[7] = fmaf(p1.w, ev, acc[7]);
      acc[8] = fmaf(p2.x, ev, acc[8]);  acc[9] = fmaf(p2.y, ev, acc[9]);
      acc[10] = fmaf(p2.z, ev, acc[10]); acc[11] = fmaf(p2.w, ev, acc[11]);
      acc[12] = fmaf(p3.x, ev, acc[12]); acc[13] = fmaf(p3.y, ev, acc[13]);
      acc[14] = fmaf(p3.z, ev, acc[14]); acc[15] = fmaf(p3.w, ev, acc[15]);
    }
#pragma unroll
    for (int i = 0; i < 8; ++i) cur[i] = nxt[i];
  }
#pragma unroll
  for (int m = 0; m < 16; ++m) sm.cx.Ps[wave][m][lane] = acc[m];
  __syncthreads();
  const int nl = tid & 63, mg = (tid >> 6) * 4;
#pragma unroll
  for (int mm = 0; mm < 4; ++mm){
    int m = mg + mm;
    float r = sm.cx.Ps[0][m][nl] + sm.cx.Ps[1][m][nl] +
              sm.cx.Ps[2][m][nl] + sm.cx.Ps[3][m][nl];
    gst(&ctx[((size_t)b * NH + m) * DIM + c0 + nl], r);
  }
  __syncthreads();
}

__global__ __launch_bounds__(256, 1) void k_mega(
    const float* __restrict__ de, const float* __restrict__ enc,
    const float* __restrict__ pk, const float* __restrict__ pv,
    const int* __restrict__ cl, const float* __restrict__ pe,
    const float* __restrict__ saqw, const float* __restrict__ sakw,
    const float* __restrict__ savw, const float* __restrict__ saow,
    const float* __restrict__ caqw, const float* __restrict__ cakw,
    const float* __restrict__ cavw, const float* __restrict__ caow,
    const float* __restrict__ saqb, const float* __restrict__ sakb,
    const float* __restrict__ savb, const float* __restrict__ saob,
    const float* __restrict__ caqb, const float* __restrict__ cakb,
    const float* __restrict__ cavb, const float* __restrict__ caob,
    const float* __restrict__ fc1w, const float* __restrict__ fc1b,
    const float* __restrict__ fc2w, const float* __restrict__ fc2b,
    const float* __restrict__ ln1w, const float* __restrict__ ln2w,
    const float* __restrict__ ln3w, const float* __restrict__ ln1b,
    const float* __restrict__ ln2b, const float* __restrict__ ln3b,
    const float* __restrict__ lmw, float* __restrict__ out,
    float* __restrict__ ws){
  __shared__ SMem sm;
  int* bar = (int*)ws;                 // leaves at [l*32], root at [512]
  float* h    = ws + 2048;             // 16384
  float* satt = ws + 18432;            // 16384
  float* gbuf = ws + 34816;            // 262144
  float* ctx  = ws + 296960;           // 262144
  float* Pqkv = ws + 559104;           // 48*BD = 786432
  float* Po   = ws + 1345536;          // 16*BD
  float* Pcq  = ws + 1607680;          // 16*BD
  float* Pvo  = ws + 1869824;          // 16*BD
  float* Pco  = ws + 2131968;          // 16*BD
  float* Pf1  = ws + 2394112;          // 4*BF = 262144
  float* Pf2  = ws + 2656256;          // 16*BD
  float* s2b  = ws + 2918400;          // 2*B*NH*SRC = 262144
  float* Plm  = ws + 3180544;          // 2*BV = 1024000
  const int blk = blockIdx.x, tid = threadIdx.x;
  int bg = 0;

  // embed
  if (blk < 16){
    int c = cl[0];
    float4 a = ((const float4*)(de + (size_t)blk * DIM))[tid];
    float4 p = ((const float4*)(pe + (size_t)c * DIM))[tid];
    float4 o;
    o.x = a.x * EMB_SCALE + p.x; o.y = a.y * EMB_SCALE + p.y;
    o.z = a.z * EMB_SCALE + p.z; o.w = a.w * EMB_SCALE + p.w;
    gst4(h + (size_t)blk * DIM + tid * 4, o);
  }
  grid_barrier(bar, ++bg);

  for (int L = 0; L < LYRS; ++L){
    const size_t wo = (size_t)L * DIM * DIM;
    const size_t bo = (size_t)L * DIM;
    const float* pk_l = pk + (size_t)L * BATCH * NCACHE * DIM;
    const float* pv_l = pv + (size_t)L * BATCH * NCACHE * DIM;
    float* ko = out + 512000 + (size_t)L * BD;
    float* vo = out + 610304 + (size_t)L * BD;
    // P1: QKV projections — 768 tiles (16x * 16z * 3y), KPB=64, 3/block
    for (int t = blk; t < 768; t += NB){
      const int x = t & 15, r = t >> 4, z = r & 15, y = r >> 4;
      const float* W = (y == 0) ? (saqw + wo) : ((y == 1) ? (sakw + wo) : (savw + wo));
      gemv_core<64, 0, false>(sm.As, h, DIM, 0, nullptr, W, DIM,
          Pqkv + (size_t)(y * 16 + z) * BD, DIM, x * 64, z * 64);
    }
    grid_barrier(bar, ++bg);
    // P2: self-attention — 256 tiles
    attn_tile(sm, blk, Pqkv, saqb + bo, sakb + bo, savb + bo, pk_l, pv_l,
              satt, ko, vo);
    grid_barrier(bar, ++bg);
    // P3: O-projection — 256 tiles (16x * 16z), KPB=64
    gemv_core<64, 0, false>(sm.As, satt, DIM, 0, nullptr, saow + wo, DIM,
        Po + (size_t)(blk >> 4) * BD, DIM, (blk & 15) * 64, (blk >> 4) * 64);
    grid_barrier(bar, ++bg);
    // P4: LN1
    if (blk < 16) ln_tile<16>(sm, blk, h, Po, BD, saob + bo, ln1w + bo, ln1b + bo, h);
    grid_barrier(bar, ++bg);
    // P5: cross-attn Q projection — 256 tiles
    gemv_core<64, 0, false>(sm.As, h, DIM, 0, nullptr, caqw + wo, DIM,
        Pcq + (size_t)(blk >> 4) * BD, DIM, (blk & 15) * 64, (blk >> 4) * 64);
    grid_barrier(bar, ++bg);
    // P6: g = qv . kw (K-projection folded into query) — 256 tiles
    gmat2_tile(sm, blk, Pcq, caqb + bo, cakw + wo, gbuf);
    grid_barrier(bar, ++bg);
    // P7: scores — 256 tiles (8x * 16b * 2z), KPB=512
    {
      const int x = blk & 7, r = blk >> 3, b = r & 15, z = r >> 4;
      gemv_core<512, 0, false>(sm.As, gbuf + (size_t)b * NH * DIM, DIM, 0, nullptr,
          enc + (size_t)b * SRCLEN * DIM, DIM,
          s2b + (size_t)z * (BATCH * NH * SRCLEN) + (size_t)b * NH * SRCLEN,
          SRCLEN, x * 64, z * 512);
    }
    grid_barrier(bar, ++bg);
    // P8: ctx with inline softmax — 256 tiles
    ctx_sm_tile(sm, blk, s2b, enc, ctx);
    grid_barrier(bar, ++bg);
    // P9: V-projection of ctx (per-head) — 256 tiles (16h * 16z), KPB=64
    {
      const int hh = blk & 15, z = blk >> 4;
      gemv_core<64, 0, false>(sm.As, ctx + (size_t)hh * DIM, NH * DIM, 0, nullptr,
          cavw + wo + (size_t)hh * HDIM * DIM, DIM,
          Pvo + (size_t)z * BD + hh * HDIM, DIM, 0, z * 64);
    }
    grid_barrier(bar, ++bg);
    // P10: cross-attn O-projection (folds Pvo + cavb) — 256 tiles, KPB=64
    gemv_core<64, 16, false>(sm.As, Pvo, DIM, BD, cavb + bo, caow + wo, DIM,
        Pco + (size_t)(blk >> 4) * BD, DIM, (blk & 15) * 64, (blk >> 4) * 64);
    grid_barrier(bar, ++bg);
    // P11: LN2
    if (blk < 16) ln_tile<16>(sm, blk, h, Pco, BD, caob + bo, ln2w + bo, ln2b + bo, h);
    grid_barrier(bar, ++bg);
    // P12: fc1 — 256 tiles (64x * 4z), KPB=256
    gemv_core<256, 0, false>(sm.As, h, DIM, 0, nullptr,
        fc1w + (size_t)L * FFNDIM * DIM, DIM,
        Pf1 + (size_t)(blk >> 6) * BF, FFNDIM, (blk & 63) * 64, (blk >> 6) * 256);
    grid_barrier(bar, ++bg);
    // P13: fc2 (folds 4 fc1 partials + bias + SiLU) — 256 tiles, KPB=256
    gemv_core<256, 4, true>(sm.As, Pf1, FFNDIM, BF, fc1b + (size_t)L * FFNDIM,
        fc2w + (size_t)L * DIM * FFNDIM, FFNDIM,
        Pf2 + (size_t)(blk >> 4) * BD, DIM, (blk & 15) * 64, (blk >> 4) * 256);
    grid_barrier(bar, ++bg);
    // P14: LN3
    if (blk < 16) ln_tile<16>(sm, blk, h, Pf2, BD, fc2b + bo, ln3w + bo, ln3b + bo, h);
    grid_barrier(bar, ++bg);
  }
  // lm_head — 1000 tiles (500x * 2z), KPB=512
  for (int t = blk; t < 1000; t += NB){
    const int x = t % 500, z = t / 500;
    gemv_core<512, 0, false>(sm.As, h, DIM, 0, nullptr, lmw, DIM,
        Plm + (size_t)z * BV, VOCAB, x * 64, z * 512);
  }
  grid_barrier(bar, ++bg);
  for (int i = blk * 256 + tid; i < BV; i += NB * 256)
    out[i] = gld(Plm + i) + gld(Plm + (size_t)BV + i);
}

extern "C" void kernel_launch(void* const* d_in, const int* in_sizes, int n_in,
                              void* d_out, int out_size, void* d_ws, size_t ws_size,
                              hipStream_t stream){
  const float* de   = (const float*)d_in[0];
  const float* enc  = (const float*)d_in[1];
  const float* pk   = (const float*)d_in[2];
  const float* pv   = (const float*)d_in[3];
  const int*   cl   = (const int*)d_in[4];
  const float* pe   = (const float*)d_in[5];
  const float* saqw = (const float*)d_in[6];
  const float* sakw = (const float*)d_in[7];
  const float* savw = (const float*)d_in[8];
  const float* saow = (const float*)d_in[9];
  const float* caqw = (const float*)d_in[10];
  const float* cakw = (const float*)d_in[11];
  const float* cavw = (const float*)d_in[12];
  const float* caow = (const float*)d_in[13];
  const float* saqb = (const float*)d_in[14];
  const float* sakb = (const float*)d_in[15];
  const float* savb = (const float*)d_in[16];
  const float* saob = (const float*)d_in[17];
  const float* caqb = (const float*)d_in[18];
  const float* cakb = (const float*)d_in[19];
  const float* cavb = (const float*)d_in[20];
  const float* caob = (const float*)d_in[21];
  const float* fc1w = (const float*)d_in[22];
  const float* fc1b = (const float*)d_in[23];
  const float* fc2w = (const float*)d_in[24];
  const float* fc2b = (const float*)d_in[25];
  const float* ln1w = (const float*)d_in[26];
  const float* ln2w = (const float*)d_in[27];
  const float* ln3w = (const float*)d_in[28];
  const float* ln1b = (const float*)d_in[29];
  const float* ln2b = (const float*)d_in[30];
  const float* ln3b = (const float*)d_in[31];
  const float* lmw  = (const float*)d_in[32];
  float* out = (float*)d_out;
  float* ws  = (float*)d_ws;

  // zero barrier leaves + root (first 8 KB of ws); graph-capture safe
  hipMemsetAsync(d_ws, 0, 8192, stream);
  k_mega<<<NB, 256, 0, stream>>>(de, enc, pk, pv, cl, pe,
      saqw, sakw, savw, saow, caqw, cakw, cavw, caow,
      saqb, sakb, savb, saob, caqb, cakb, cavb, caob,
      fc1w, fc1b, fc2w, fc2b, ln1w, ln2w, ln3w, ln1b, ln2b, ln3b,
      lmw, out, ws);
}

// Round 8
// 847.277 us; speedup vs baseline: 2.8210x; 2.8210x over previous
//
#include <hip/hip_runtime.h>
#include <math.h>

#define LYRS 6
#define BATCH 16
#define DIM 1024
#define NH 16
#define HDIM 64
#define FFNDIM 4096
#define VOCAB 32000
#define NCACHE 512
#define SRCLEN 512
#define SCALE 0.125f
#define EMB_SCALE 32.0f
#define BD (BATCH * DIM)
#define BF (BATCH * FFNDIM)
#define BV (BATCH * VOCAB)

__device__ __forceinline__ float wave_reduce_sum(float v){
#pragma unroll
  for (int off = 32; off; off >>= 1) v += __shfl_xor(v, off, 64);
  return v;
}
__device__ __forceinline__ float wave_reduce_max(float v){
#pragma unroll
  for (int off = 32; off; off >>= 1) v = fmaxf(v, __shfl_xor(v, off, 64));
  return v;
}
__device__ __forceinline__ float4 silu4(float4 v){
  v.x = v.x / (1.f + __expf(-v.x));
  v.y = v.y / (1.f + __expf(-v.y));
  v.z = v.z / (1.f + __expf(-v.z));
  v.w = v.w / (1.f + __expf(-v.w));
  return v;
}

// h[b][d] = decoder_embed[b][d]*sqrt(D) + pe[cache_len][d]
__global__ __launch_bounds__(256) void k_embed(const float* __restrict__ de,
                                               const float* __restrict__ pe,
                                               const int* __restrict__ cl,
                                               float* __restrict__ h){
  int b = blockIdx.x, t = threadIdx.x;
  int c = cl[0];
  const float4* d4 = (const float4*)(de + (size_t)b * DIM);
  const float4* p4 = (const float4*)(pe + (size_t)c * DIM);
  float4* h4 = (float4*)(h + (size_t)b * DIM);
  float4 a = d4[t], p = p4[t];
  float4 o;
  o.x = a.x * EMB_SCALE + p.x; o.y = a.y * EMB_SCALE + p.y;
  o.z = a.z * EMB_SCALE + p.z; o.w = a.w * EMB_SCALE + p.w;
  h4[t] = o;
}

// ---------------------------------------------------------------------------
// m-split GEMV core (R4-proven). Block: 256 threads / 4 waves, n-tile of 64
// (lane-owned), k-range [k0, k0+KPB). Waves split M (4 rows each), share the
// W stream (L2 absorbs re-read). A staged in LDS k-major; optional fold of
// NZ k-split partial slabs + k-indexed bias + SiLU during staging.
// ---------------------------------------------------------------------------
template<int KPB, int NZ, bool SILU>
__device__ __forceinline__ void gemv_ms_core(
    const float* __restrict__ Asrc, int a_rs, int pz,
    const float* __restrict__ abias,
    const float* __restrict__ W, int w_rs,
    float* __restrict__ Cz, int c_rs,
    int n0, int k0){
  __shared__ float As[16][KPB];
  const int tid = threadIdx.x;
  {
    const int m = tid >> 4;
    const int q0 = (tid & 15) * 4;
    constexpr int QPT = KPB / 64;
#pragma unroll
    for (int qq = 0; qq < QPT; ++qq){
      const int q = q0 + qq * 64;
      const int gk = k0 + q;
      float4 v;
      if (NZ == 0){
        v = *(const float4*)(Asrc + (size_t)m * a_rs + gk);
      } else {
        if (abias) v = *(const float4*)(abias + gk);
        else { v.x = 0.f; v.y = 0.f; v.z = 0.f; v.w = 0.f; }
#pragma unroll
        for (int z = 0; z < NZ; ++z){
          float4 pv = *(const float4*)(Asrc + (size_t)z * pz + (size_t)m * a_rs + gk);
          v.x += pv.x; v.y += pv.y; v.z += pv.z; v.w += pv.w;
        }
      }
      if (SILU) v = silu4(v);
      *(float4*)(&As[m][q]) = v;
    }
  }
  __syncthreads();
  const int lane = tid & 63;
  const int m0 = (tid >> 6) * 4;
  const float* Wrow = W + (size_t)(n0 + lane) * w_rs + k0;
  float acc0 = 0.f, acc1 = 0.f, acc2 = 0.f, acc3 = 0.f;
  constexpr int CHUNKS = KPB / 64;
  float4 wb[2][16];
#pragma unroll
  for (int c = 0; c < 16; ++c) wb[0][c] = *(const float4*)(Wrow + c * 4);
#pragma unroll
  for (int ch = 0; ch < CHUNKS; ++ch){
    const int cur = ch & 1;
    if (ch + 1 < CHUNKS){
#pragma unroll
      for (int c = 0; c < 16; ++c)
        wb[cur ^ 1][c] = *(const float4*)(Wrow + (ch + 1) * 64 + c * 4);
    }
#pragma unroll
    for (int c = 0; c < 16; ++c){
      float4 wv = wb[cur][c];
      const int q = ch * 64 + c * 4;
      float4 a0 = *(const float4*)(&As[m0 + 0][q]);
      float4 a1 = *(const float4*)(&As[m0 + 1][q]);
      float4 a2 = *(const float4*)(&As[m0 + 2][q]);
      float4 a3 = *(const float4*)(&As[m0 + 3][q]);
      acc0 = fmaf(wv.x, a0.x, acc0); acc0 = fmaf(wv.y, a0.y, acc0);
      acc0 = fmaf(wv.z, a0.z, acc0); acc0 = fmaf(wv.w, a0.w, acc0);
      acc1 = fmaf(wv.x, a1.x, acc1); acc1 = fmaf(wv.y, a1.y, acc1);
      acc1 = fmaf(wv.z, a1.z, acc1); acc1 = fmaf(wv.w, a1.w, acc1);
      acc2 = fmaf(wv.x, a2.x, acc2); acc2 = fmaf(wv.y, a2.y, acc2);
      acc2 = fmaf(wv.z, a2.z, acc2); acc2 = fmaf(wv.w, a2.w, acc2);
      acc3 = fmaf(wv.x, a3.x, acc3); acc3 = fmaf(wv.y, a3.y, acc3);
      acc3 = fmaf(wv.z, a3.z, acc3); acc3 = fmaf(wv.w, a3.w, acc3);
    }
  }
  Cz[(size_t)(m0 + 0) * c_rs + n0 + lane] = acc0;
  Cz[(size_t)(m0 + 1) * c_rs + n0 + lane] = acc1;
  Cz[(size_t)(m0 + 2) * c_rs + n0 + lane] = acc2;
  Cz[(size_t)(m0 + 3) * c_rs + n0 + lane] = acc3;
}

template<int KPB, int NZ, bool SILU>
__global__ __launch_bounds__(256) void k_gemv_ms(
    const float* __restrict__ A, int a_rs, int a_bs, int pz,
    const float* __restrict__ abias,
    const float* __restrict__ W, int w_rs, int w_bs,
    float* __restrict__ C, int c_rs, int c_bs, int c_zs){
  const int bb = blockIdx.y;
  gemv_ms_core<KPB, NZ, SILU>(A + (size_t)bb * a_bs, a_rs, pz, abias,
      W + (size_t)bb * w_bs, w_rs,
      C + (size_t)blockIdx.z * c_zs + (size_t)bb * c_bs, c_rs,
      blockIdx.x * 64, blockIdx.z * KPB);
}

// QKV fused: blockIdx.y selects weight matrix / output slab group (z=8).
template<int KPB>
__global__ __launch_bounds__(256) void k_gemv_ms3(
    const float* __restrict__ A, const float* __restrict__ W0,
    const float* __restrict__ W1, const float* __restrict__ W2,
    float* __restrict__ C){
  const int y = blockIdx.y;
  const float* W = (y == 0) ? W0 : ((y == 1) ? W1 : W2);
  gemv_ms_core<KPB, 0, false>(A, DIM, 0, nullptr, W, DIM,
      C + ((size_t)y * 8 + blockIdx.z) * BD, DIM,
      blockIdx.x * 64, blockIdx.z * KPB);
}

// lm_head partial combine: out[i] = P[0][i] + P[1][i]
__global__ __launch_bounds__(256) void k_fin2(const float* __restrict__ P,
                                              float* __restrict__ out){
  int i = blockIdx.x * 256 + threadIdx.x;
  out[i] = P[i] + P[(size_t)BV + i];
}

// Self-attention per (b,h). Folds the 8 QKV k-split partials (+bias),
// writes new k/v to d_out, attends over 513 keys (float4-vectorized,
// 4 rows per wave-iter, prefetched). Mask bias is softmax-invariant.
__global__ __launch_bounds__(512) void k_self_attn(
    const float* __restrict__ Pqkv, const float* __restrict__ qb_,
    const float* __restrict__ kb_, const float* __restrict__ vb_,
    const float* __restrict__ pk, const float* __restrict__ pv,
    float* __restrict__ satt, float* __restrict__ out_k,
    float* __restrict__ out_v){
  __shared__ float qs[64], ks[64], vs[64];
  __shared__ float sc[513];
  __shared__ float red1[8], red2[8];
  __shared__ float o8[8][64];
  const int bh = blockIdx.x, b = bh >> 4, h = bh & 15;
  const int tid = threadIdx.x, w = tid >> 6, lane = tid & 63;
  const int hd = h * HDIM + lane;
  if (w < 3){
    const float* Pz = Pqkv + (size_t)w * (8 * BD);
    const float* bias = (w == 0) ? qb_ : ((w == 1) ? kb_ : vb_);
    float v = bias[hd];
#pragma unroll
    for (int z = 0; z < 8; ++z)
      v += Pz[(size_t)z * BD + b * DIM + hd];
    if (w == 0) qs[lane] = v * SCALE;
    else if (w == 1){ ks[lane] = v; out_k[b * DIM + hd] = v; }
    else { vs[lane] = v; out_v[b * DIM + hd] = v; }
  }
  __syncthreads();
  const int jj = lane >> 4, c = lane & 15;
  float4 q4 = *(const float4*)(&qs[c * 4]);
  const float* kbase = pk + (size_t)b * NCACHE * DIM + h * HDIM + c * 4;
  {
    float4 nk = *(const float4*)(kbase + (size_t)(w * 4 + jj) * DIM);
    for (int it = 0; it < 16; ++it){
      int j = it * 32 + w * 4 + jj;
      float4 K4 = nk;
      if (it < 15) nk = *(const float4*)(kbase + (size_t)(j + 32) * DIM);
      float r = q4.x * K4.x;
      r = fmaf(q4.y, K4.y, r); r = fmaf(q4.z, K4.z, r); r = fmaf(q4.w, K4.w, r);
      r += __shfl_xor(r, 1, 64); r += __shfl_xor(r, 2, 64);
      r += __shfl_xor(r, 4, 64); r += __shfl_xor(r, 8, 64);
      if (c == 0) sc[j] = r;
    }
  }
  if (w == 0 && lane < 16){
    float4 k4 = *(const float4*)(&ks[lane * 4]);
    float r = q4.x * k4.x;
    r = fmaf(q4.y, k4.y, r); r = fmaf(q4.z, k4.z, r); r = fmaf(q4.w, k4.w, r);
    r += __shfl_xor(r, 1, 64); r += __shfl_xor(r, 2, 64);
    r += __shfl_xor(r, 4, 64); r += __shfl_xor(r, 8, 64);
    if (lane == 0) sc[512] = r;
  }
  __syncthreads();
  float lm = -1e30f;
  for (int j2 = tid; j2 < 513; j2 += 512) lm = fmaxf(lm, sc[j2]);
  lm = wave_reduce_max(lm);
  if (lane == 0) red1[w] = lm;
  __syncthreads();
  float bm = red1[0];
#pragma unroll
  for (int ww = 1; ww < 8; ++ww) bm = fmaxf(bm, red1[ww]);
  float ls = 0.f;
  for (int j2 = tid; j2 < 513; j2 += 512){
    float e = __expf(sc[j2] - bm);
    sc[j2] = e;
    ls += e;
  }
  ls = wave_reduce_sum(ls);
  if (lane == 0) red2[w] = ls;
  __syncthreads();
  float tot = 0.f;
#pragma unroll
  for (int ww = 0; ww < 8; ++ww) tot += red2[ww];
  float inv = 1.f / tot;
  const float* vbase = pv + (size_t)b * NCACHE * DIM + h * HDIM + c * 4;
  float4 acc; acc.x = 0.f; acc.y = 0.f; acc.z = 0.f; acc.w = 0.f;
  {
    float4 nv = *(const float4*)(vbase + (size_t)(w * 4 + jj) * DIM);
    for (int it = 0; it < 16; ++it){
      int j = it * 32 + w * 4 + jj;
      float4 V4 = nv;
      if (it < 15) nv = *(const float4*)(vbase + (size_t)(j + 32) * DIM);
      float pj = sc[j];
      acc.x = fmaf(pj, V4.x, acc.x); acc.y = fmaf(pj, V4.y, acc.y);
      acc.z = fmaf(pj, V4.z, acc.z); acc.w = fmaf(pj, V4.w, acc.w);
    }
  }
  if (w == 0 && lane < 16){
    float p512 = sc[512];
    float4 v4 = *(const float4*)(&vs[lane * 4]);
    acc.x = fmaf(p512, v4.x, acc.x); acc.y = fmaf(p512, v4.y, acc.y);
    acc.z = fmaf(p512, v4.z, acc.z); acc.w = fmaf(p512, v4.w, acc.w);
  }
  acc.x += __shfl_xor(acc.x, 16, 64); acc.x += __shfl_xor(acc.x, 32, 64);
  acc.y += __shfl_xor(acc.y, 16, 64); acc.y += __shfl_xor(acc.y, 32, 64);
  acc.z += __shfl_xor(acc.z, 16, 64); acc.z += __shfl_xor(acc.z, 32, 64);
  acc.w += __shfl_xor(acc.w, 16, 64); acc.w += __shfl_xor(acc.w, 32, 64);
  if (lane < 16){
    o8[w][lane * 4 + 0] = acc.x; o8[w][lane * 4 + 1] = acc.y;
    o8[w][lane * 4 + 2] = acc.z; o8[w][lane * 4 + 3] = acc.w;
  }
  __syncthreads();
  if (tid < 64){
    float s2 = 0.f;
#pragma unroll
    for (int ww = 0; ww < 8; ++ww) s2 += o8[ww][tid];
    satt[b * DIM + h * HDIM + tid] = s2 * inv;
  }
}

// h = LayerNorm(res + sum_z P[z] + obias) * w + b
template<int NZ>
__global__ __launch_bounds__(256) void k_add_ln_pz(
    const float* __restrict__ res, const float* __restrict__ P, int zs,
    const float* __restrict__ obias, const float* __restrict__ w,
    const float* __restrict__ bln, float* __restrict__ outh){
  __shared__ float r1[4], r2[4];
  int b = blockIdx.x, tid = threadIdx.x, wave = tid >> 6, lane = tid & 63;
  float4 rv = ((const float4*)(res + (size_t)b * DIM))[tid];
  float4 ob = ((const float4*)obias)[tid];
  float v0 = rv.x + ob.x, v1 = rv.y + ob.y, v2 = rv.z + ob.z, v3 = rv.w + ob.w;
#pragma unroll
  for (int z = 0; z < NZ; ++z){
    float4 pz = ((const float4*)(P + (size_t)z * zs + (size_t)b * DIM))[tid];
    v0 += pz.x; v1 += pz.y; v2 += pz.z; v3 += pz.w;
  }
  float s = v0 + v1 + v2 + v3;
  float sq = v0 * v0 + v1 * v1 + v2 * v2 + v3 * v3;
  s = wave_reduce_sum(s); sq = wave_reduce_sum(sq);
  if (lane == 0){ r1[wave] = s; r2[wave] = sq; }
  __syncthreads();
  float ts = r1[0] + r1[1] + r1[2] + r1[3];
  float tq = r2[0] + r2[1] + r2[2] + r2[3];
  float mean = ts * (1.f / DIM);
  float var = tq * (1.f / DIM) - mean * mean;
  float rstd = rsqrtf(var + 1e-5f);
  float4 wv = ((const float4*)w)[tid], bv = ((const float4*)bln)[tid];
  float4 o;
  o.x = (v0 - mean) * rstd * wv.x + bv.x;
  o.y = (v1 - mean) * rstd * wv.y + bv.y;
  o.z = (v2 - mean) * rstd * wv.z + bv.z;
  o.w = (v3 - mean) * rstd * wv.w + bv.w;
  ((float4*)(outh + (size_t)b * DIM))[tid] = o;
}

// g[b][h][c] = sum_d qv[b][hd] * kw[hd][c], qv = (sum16 Pcq + caqb)*SCALE
__global__ __launch_bounds__(256) void k_gmat2(
    const float* __restrict__ Pcq, const float* __restrict__ caqb,
    const float* __restrict__ kw, float* __restrict__ g){
  __shared__ float qsT[64][16];   // [d][b]
  __shared__ float Ps[4][16][64];
  const int h = blockIdx.y, c0 = blockIdx.x * 64;
  const int tid = threadIdx.x, lane = tid & 63, wave = tid >> 6;
  {
    const int b = tid >> 4, q0 = (tid & 15) * 4;
    float4 v = *(const float4*)(caqb + h * HDIM + q0);
#pragma unroll
    for (int z = 0; z < 16; ++z){
      float4 pv = *(const float4*)(Pcq + (size_t)z * BD +
                                   (size_t)b * DIM + h * HDIM + q0);
      v.x += pv.x; v.y += pv.y; v.z += pv.z; v.w += pv.w;
    }
    qsT[q0 + 0][b] = v.x * SCALE; qsT[q0 + 1][b] = v.y * SCALE;
    qsT[q0 + 2][b] = v.z * SCALE; qsT[q0 + 3][b] = v.w * SCALE;
  }
  __syncthreads();
  float wv[16];
#pragma unroll
  for (int dd = 0; dd < 16; ++dd)
    wv[dd] = kw[(size_t)(h * HDIM + wave * 16 + dd) * DIM + c0 + lane];
  float acc[16];
#pragma unroll
  for (int m = 0; m < 16; ++m) acc[m] = 0.f;
#pragma unroll
  for (int dd = 0; dd < 16; ++dd){
    const int d = wave * 16 + dd;
    float4 a0 = *(const float4*)(&qsT[d][0]);
    float4 a1 = *(const float4*)(&qsT[d][4]);
    float4 a2 = *(const float4*)(&qsT[d][8]);
    float4 a3 = *(const float4*)(&qsT[d][12]);
    float wd = wv[dd];
    acc[0] = fmaf(wd, a0.x, acc[0]);  acc[1] = fmaf(wd, a0.y, acc[1]);
    acc[2] = fmaf(wd, a0.z, acc[2]);  acc[3] = fmaf(wd, a0.w, acc[3]);
    acc[4] = fmaf(wd, a1.x, acc[4]);  acc[5] = fmaf(wd, a1.y, acc[5]);
    acc[6] = fmaf(wd, a1.z, acc[6]);  acc[7] = fmaf(wd, a1.w, acc[7]);
    acc[8] = fmaf(wd, a2.x, acc[8]);  acc[9] = fmaf(wd, a2.y, acc[9]);
    acc[10] = fmaf(wd, a2.z, acc[10]); acc[11] = fmaf(wd, a2.w, acc[11]);
    acc[12] = fmaf(wd, a3.x, acc[12]); acc[13] = fmaf(wd, a3.y, acc[13]);
    acc[14] = fmaf(wd, a3.z, acc[14]); acc[15] = fmaf(wd, a3.w, acc[15]);
  }
#pragma unroll
  for (int m = 0; m < 16; ++m) Ps[wave][m][lane] = acc[m];
  __syncthreads();
  const int nl = tid & 63, mg = (tid >> 6) * 4;
#pragma unroll
  for (int mm = 0; mm < 4; ++mm){
    int m = mg + mm;
    float r = Ps[0][m][nl] + Ps[1][m][nl] + Ps[2][m][nl] + Ps[3][m][nl];
    g[((size_t)m * NH + h) * DIM + c0 + nl] = r;
  }
}

// ctx with INLINE softmax: stages p = softmax(sum of 8 score slabs) into
// LDS transposed, then ctx[b][h][c] = sum_j p[b][h][j]*enc[b][j][c].
// grid: (16 c-tiles, 16 b)
__global__ __launch_bounds__(256) void k_ctx_sm(
    const float* __restrict__ s2b, const float* __restrict__ enc,
    float* __restrict__ ctx){
  __shared__ float pT[SRCLEN][16];
  __shared__ float Ps[4][16][64];
  const int b = blockIdx.y, c0 = blockIdx.x * 64;
  const int tid = threadIdx.x, lane = tid & 63, wave = tid >> 6;
  {
    const int h = tid >> 4, jp = (tid & 15) * 4;
    const size_t row = ((size_t)b * NH + h) * SRCLEN;
    float4 val[8];
    float vmax = -1e30f;
#pragma unroll
    for (int t = 0; t < 8; ++t){
      const int j = jp + t * 64;
      float4 v = *(const float4*)(s2b + row + j);
#pragma unroll
      for (int z = 1; z < 8; ++z){
        float4 v2 = *(const float4*)(s2b + (size_t)z * (BATCH * NH * SRCLEN) + row + j);
        v.x += v2.x; v.y += v2.y; v.z += v2.z; v.w += v2.w;
      }
      val[t] = v;
      vmax = fmaxf(vmax, fmaxf(fmaxf(v.x, v.y), fmaxf(v.z, v.w)));
    }
#pragma unroll
    for (int o = 1; o <= 8; o <<= 1) vmax = fmaxf(vmax, __shfl_xor(vmax, o, 64));
    float lsum = 0.f;
#pragma unroll
    for (int t = 0; t < 8; ++t){
      val[t].x = __expf(val[t].x - vmax); val[t].y = __expf(val[t].y - vmax);
      val[t].z = __expf(val[t].z - vmax); val[t].w = __expf(val[t].w - vmax);
      lsum += val[t].x + val[t].y + val[t].z + val[t].w;
    }
#pragma unroll
    for (int o = 1; o <= 8; o <<= 1) lsum += __shfl_xor(lsum, o, 64);
    float inv = 1.f / lsum;
#pragma unroll
    for (int t = 0; t < 8; ++t){
      const int j = jp + t * 64;
      pT[j + 0][h] = val[t].x * inv; pT[j + 1][h] = val[t].y * inv;
      pT[j + 2][h] = val[t].z * inv; pT[j + 3][h] = val[t].w * inv;
    }
  }
  __syncthreads();
  const float* ep = enc + (size_t)b * SRCLEN * DIM + c0 + lane;
  const int jb = wave * 128;
  float acc[16];
#pragma unroll
  for (int m = 0; m < 16; ++m) acc[m] = 0.f;
  float cur[8], nxt[8];
#pragma unroll
  for (int i = 0; i < 8; ++i) cur[i] = ep[(size_t)(jb + i) * DIM];
#pragma unroll
  for (int t = 0; t < 16; ++t){
    if (t < 15){
#pragma unroll
      for (int i = 0; i < 8; ++i)
        nxt[i] = ep[(size_t)(jb + (t + 1) * 8 + i) * DIM];
    }
#pragma unroll
    for (int i = 0; i < 8; ++i){
      const int j = jb + t * 8 + i;
      float4 p0 = *(const float4*)(&pT[j][0]);
      float4 p1 = *(const float4*)(&pT[j][4]);
      float4 p2 = *(const float4*)(&pT[j][8]);
      float4 p3 = *(const float4*)(&pT[j][12]);
      float ev = cur[i];
      acc[0] = fmaf(p0.x, ev, acc[0]);  acc[1] = fmaf(p0.y, ev, acc[1]);
      acc[2] = fmaf(p0.z, ev, acc[2]);  acc[3] = fmaf(p0.w, ev, acc[3]);
      acc[4] = fmaf(p1.x, ev, acc[4]);  acc[5] = fmaf(p1.y, ev, acc[5]);
      acc[6] = fmaf(p1.z, ev, acc[6]);  acc[7] = fmaf(p1.w, ev, acc[7]);
      acc[8] = fmaf(p2.x, ev, acc[8]);  acc[9] = fmaf(p2.y, ev, acc[9]);
      acc[10] = fmaf(p2.z, ev, acc[10]); acc[11] = fmaf(p2.w, ev, acc[11]);
      acc[12] = fmaf(p3.x, ev, acc[12]); acc[13] = fmaf(p3.y, ev, acc[13]);
      acc[14] = fmaf(p3.z, ev, acc[14]); acc[15] = fmaf(p3.w, ev, acc[15]);
    }
#pragma unroll
    for (int i = 0; i < 8; ++i) cur[i] = nxt[i];
  }
#pragma unroll
  for (int m = 0; m < 16; ++m) Ps[wave][m][lane] = acc[m];
  __syncthreads();
  const int nl = tid & 63, mg = (tid >> 6) * 4;
#pragma unroll
  for (int mm = 0; mm < 4; ++mm){
    int m = mg + mm;
    float r = Ps[0][m][nl] + Ps[1][m][nl] + Ps[2][m][nl] + Ps[3][m][nl];
    ctx[((size_t)b * NH + m) * DIM + c0 + nl] = r;
  }
}

extern "C" void kernel_launch(void* const* d_in, const int* in_sizes, int n_in,
                              void* d_out, int out_size, void* d_ws, size_t ws_size,
                              hipStream_t stream){
  const float* de   = (const float*)d_in[0];
  const float* enc  = (const float*)d_in[1];
  const float* pk   = (const float*)d_in[2];
  const float* pv   = (const float*)d_in[3];
  const int*   cl   = (const int*)d_in[4];
  const float* pe   = (const float*)d_in[5];
  const float* saqw = (const float*)d_in[6];
  const float* sakw = (const float*)d_in[7];
  const float* savw = (const float*)d_in[8];
  const float* saow = (const float*)d_in[9];
  const float* caqw = (const float*)d_in[10];
  const float* cakw = (const float*)d_in[11];
  const float* cavw = (const float*)d_in[12];
  const float* caow = (const float*)d_in[13];
  const float* saqb = (const float*)d_in[14];
  const float* sakb = (const float*)d_in[15];
  const float* savb = (const float*)d_in[16];
  const float* saob = (const float*)d_in[17];
  const float* caqb = (const float*)d_in[18];
  const float* cakb = (const float*)d_in[19];
  const float* cavb = (const float*)d_in[20];
  const float* caob = (const float*)d_in[21];
  const float* fc1w = (const float*)d_in[22];
  const float* fc1b = (const float*)d_in[23];
  const float* fc2w = (const float*)d_in[24];
  const float* fc2b = (const float*)d_in[25];
  const float* ln1w = (const float*)d_in[26];
  const float* ln2w = (const float*)d_in[27];
  const float* ln3w = (const float*)d_in[28];
  const float* ln1b = (const float*)d_in[29];
  const float* ln2b = (const float*)d_in[30];
  const float* ln3b = (const float*)d_in[31];
  const float* lmw  = (const float*)d_in[32];
  float* out = (float*)d_out;
  float* ws  = (float*)d_ws;

  float* h    = ws;              // [16][1024]
  float* satt = ws + 16384;      // [16][1024]
  float* g    = ws + 32768;      // [16][16][1024]
  float* ctx  = ws + 294912;     // [16][16][1024]
  float* Pqkv = ws + 557056;     // [3][8][16][1024]
  float* Po   = ws + 950272;     // [16][16][1024]
  float* Pcq  = ws + 1212416;    // [16][16][1024]
  float* Pvo  = ws + 1474560;    // [16][16][1024]
  float* Pco  = ws + 1736704;    // [16][16][1024]
  float* Pf1  = ws + 1998848;    // [8][16][4096]
  float* Pf2  = ws + 2523136;    // [32][16][1024]
  float* s2b  = ws + 3047424;    // [8][256][512]
  float* Plm  = ws + 4096000;    // [2][16][32000]

  float* out_k = out + 512000;   // [L][16][1024]
  float* out_v = out + 610304;   // [L][16][1024]

  k_embed<<<16, 256, 0, stream>>>(de, pe, cl, h);

  for (int i = 0; i < LYRS; ++i){
    size_t wo = (size_t)i * DIM * DIM;
    size_t bo = (size_t)i * DIM;
    float* ko = out_k + (size_t)i * BD;
    float* vo = out_v + (size_t)i * BD;
    // ---- self-attention ----
    k_gemv_ms3<128><<<dim3(16, 3, 8), 256, 0, stream>>>(h, saqw + wo, sakw + wo,
        savw + wo, Pqkv);
    k_self_attn<<<256, 512, 0, stream>>>(Pqkv, saqb + bo, sakb + bo, savb + bo,
        pk + (size_t)i * BATCH * NCACHE * DIM, pv + (size_t)i * BATCH * NCACHE * DIM,
        satt, ko, vo);
    k_gemv_ms<64, 0, false><<<dim3(16, 1, 16), 256, 0, stream>>>(satt, DIM, 0, 0,
        nullptr, saow + wo, DIM, 0, Po, DIM, 0, BD);
    k_add_ln_pz<16><<<16, 256, 0, stream>>>(h, Po, BD, saob + bo,
        ln1w + bo, ln1b + bo, h);
    // ---- cross-attention (K/V projections folded around the softmax) ----
    k_gemv_ms<64, 0, false><<<dim3(16, 1, 16), 256, 0, stream>>>(h, DIM, 0, 0,
        nullptr, caqw + wo, DIM, 0, Pcq, DIM, 0, BD);
    k_gmat2<<<dim3(16, 16), 256, 0, stream>>>(Pcq, caqb + bo, cakw + wo, g);
    k_gemv_ms<128, 0, false><<<dim3(8, 16, 8), 256, 0, stream>>>(g, DIM, NH * DIM,
        0, nullptr, enc, DIM, SRCLEN * DIM, s2b, SRCLEN, NH * SRCLEN,
        BATCH * NH * SRCLEN);
    k_ctx_sm<<<dim3(16, 16), 256, 0, stream>>>(s2b, enc, ctx);
    k_gemv_ms<64, 0, false><<<dim3(1, 16, 16), 256, 0, stream>>>(ctx, NH * DIM,
        DIM, 0, nullptr, cavw + wo, DIM, HDIM * DIM, Pvo, DIM, HDIM, BD);
    k_gemv_ms<64, 16, false><<<dim3(16, 1, 16), 256, 0, stream>>>(Pvo, DIM, 0,
        BD, cavb + bo, caow + wo, DIM, 0, Pco, DIM, 0, BD);
    k_add_ln_pz<16><<<16, 256, 0, stream>>>(h, Pco, BD, caob + bo,
        ln2w + bo, ln2b + bo, h);
    // ---- FFN ----
    k_gemv_ms<128, 0, false><<<dim3(64, 1, 8), 256, 0, stream>>>(h, DIM, 0, 0,
        nullptr, fc1w + (size_t)i * FFNDIM * DIM, DIM, 0, Pf1, FFNDIM, 0, BF);
    k_gemv_ms<128, 8, true><<<dim3(16, 1, 32), 256, 0, stream>>>(Pf1, FFNDIM, 0,
        BF, fc1b + (size_t)i * FFNDIM,
        fc2w + (size_t)i * DIM * FFNDIM, FFNDIM, 0, Pf2, DIM, 0, BD);
    k_add_ln_pz<32><<<16, 256, 0, stream>>>(h, Pf2, BD, fc2b + bo,
        ln3w + bo, ln3b + bo, h);
  }
  // ---- lm_head ----
  k_gemv_ms<512, 0, false><<<dim3(VOCAB / 64, 1, 2), 256, 0, stream>>>(h, DIM, 0,
      0, nullptr, lmw, DIM, 0, Plm, VOCAB, 0, BV);
  k_fin2<<<BV / 256, 256, 0, stream>>>(Plm, out);
}

// Round 9
// 847.069 us; speedup vs baseline: 2.8217x; 1.0002x over previous
//
#include <hip/hip_runtime.h>
#include <math.h>

#define LYRS 6
#define BATCH 16
#define DIM 1024
#define NH 16
#define HDIM 64
#define FFNDIM 4096
#define VOCAB 32000
#define NCACHE 512
#define SRCLEN 512
#define SCALE 0.125f
#define EMB_SCALE 32.0f
#define BD (BATCH * DIM)
#define BF (BATCH * FFNDIM)
#define BV (BATCH * VOCAB)

__device__ __forceinline__ float wave_reduce_sum(float v){
#pragma unroll
  for (int off = 32; off; off >>= 1) v += __shfl_xor(v, off, 64);
  return v;
}
__device__ __forceinline__ float wave_reduce_max(float v){
#pragma unroll
  for (int off = 32; off; off >>= 1) v = fmaxf(v, __shfl_xor(v, off, 64));
  return v;
}
__device__ __forceinline__ float4 silu4(float4 v){
  v.x = v.x / (1.f + __expf(-v.x));
  v.y = v.y / (1.f + __expf(-v.y));
  v.z = v.z / (1.f + __expf(-v.z));
  v.w = v.w / (1.f + __expf(-v.w));
  return v;
}

// h[b][d] = decoder_embed[b][d]*sqrt(D) + pe[cache_len][d]
__global__ __launch_bounds__(256) void k_embed(const float* __restrict__ de,
                                               const float* __restrict__ pe,
                                               const int* __restrict__ cl,
                                               float* __restrict__ h){
  int b = blockIdx.x, t = threadIdx.x;
  int c = cl[0];
  const float4* d4 = (const float4*)(de + (size_t)b * DIM);
  const float4* p4 = (const float4*)(pe + (size_t)c * DIM);
  float4* h4 = (float4*)(h + (size_t)b * DIM);
  float4 a = d4[t], p = p4[t];
  float4 o;
  o.x = a.x * EMB_SCALE + p.x; o.y = a.y * EMB_SCALE + p.y;
  o.z = a.z * EMB_SCALE + p.z; o.w = a.w * EMB_SCALE + p.w;
  h4[t] = o;
}

// ---------------------------------------------------------------------------
// m-split GEMV core. Block: 256 threads / 4 waves, n-tile of 64 (lane-owned),
// k-range [k0, k0+KPB). Waves split M (4 rows each), share the W stream.
// A staged in LDS k-major; optional fold of NZ k-split partial slabs +
// k-indexed bias + SiLU during staging. W loads double-buffered (CHUNKS>=2).
// ---------------------------------------------------------------------------
template<int KPB, int NZ, bool SILU>
__device__ __forceinline__ void gemv_ms_core(
    const float* __restrict__ Asrc, int a_rs, int pz,
    const float* __restrict__ abias,
    const float* __restrict__ W, int w_rs,
    float* __restrict__ Cz, int c_rs,
    int n0, int k0){
  __shared__ float As[16][KPB];
  const int tid = threadIdx.x;
  {
    const int m = tid >> 4;
    const int q0 = (tid & 15) * 4;
    constexpr int QPT = KPB / 64;
#pragma unroll
    for (int qq = 0; qq < QPT; ++qq){
      const int q = q0 + qq * 64;
      const int gk = k0 + q;
      float4 v;
      if (NZ == 0){
        v = *(const float4*)(Asrc + (size_t)m * a_rs + gk);
      } else {
        if (abias) v = *(const float4*)(abias + gk);
        else { v.x = 0.f; v.y = 0.f; v.z = 0.f; v.w = 0.f; }
#pragma unroll
        for (int z = 0; z < NZ; ++z){
          float4 pv = *(const float4*)(Asrc + (size_t)z * pz + (size_t)m * a_rs + gk);
          v.x += pv.x; v.y += pv.y; v.z += pv.z; v.w += pv.w;
        }
      }
      if (SILU) v = silu4(v);
      *(float4*)(&As[m][q]) = v;
    }
  }
  __syncthreads();
  const int lane = tid & 63;
  const int m0 = (tid >> 6) * 4;
  const float* Wrow = W + (size_t)(n0 + lane) * w_rs + k0;
  float acc0 = 0.f, acc1 = 0.f, acc2 = 0.f, acc3 = 0.f;
  constexpr int CHUNKS = KPB / 64;
  float4 wb[2][16];
#pragma unroll
  for (int c = 0; c < 16; ++c) wb[0][c] = *(const float4*)(Wrow + c * 4);
#pragma unroll
  for (int ch = 0; ch < CHUNKS; ++ch){
    const int cur = ch & 1;
    if (ch + 1 < CHUNKS){
#pragma unroll
      for (int c = 0; c < 16; ++c)
        wb[cur ^ 1][c] = *(const float4*)(Wrow + (ch + 1) * 64 + c * 4);
    }
#pragma unroll
    for (int c = 0; c < 16; ++c){
      float4 wv = wb[cur][c];
      const int q = ch * 64 + c * 4;
      float4 a0 = *(const float4*)(&As[m0 + 0][q]);
      float4 a1 = *(const float4*)(&As[m0 + 1][q]);
      float4 a2 = *(const float4*)(&As[m0 + 2][q]);
      float4 a3 = *(const float4*)(&As[m0 + 3][q]);
      acc0 = fmaf(wv.x, a0.x, acc0); acc0 = fmaf(wv.y, a0.y, acc0);
      acc0 = fmaf(wv.z, a0.z, acc0); acc0 = fmaf(wv.w, a0.w, acc0);
      acc1 = fmaf(wv.x, a1.x, acc1); acc1 = fmaf(wv.y, a1.y, acc1);
      acc1 = fmaf(wv.z, a1.z, acc1); acc1 = fmaf(wv.w, a1.w, acc1);
      acc2 = fmaf(wv.x, a2.x, acc2); acc2 = fmaf(wv.y, a2.y, acc2);
      acc2 = fmaf(wv.z, a2.z, acc2); acc2 = fmaf(wv.w, a2.w, acc2);
      acc3 = fmaf(wv.x, a3.x, acc3); acc3 = fmaf(wv.y, a3.y, acc3);
      acc3 = fmaf(wv.z, a3.z, acc3); acc3 = fmaf(wv.w, a3.w, acc3);
    }
  }
  Cz[(size_t)(m0 + 0) * c_rs + n0 + lane] = acc0;
  Cz[(size_t)(m0 + 1) * c_rs + n0 + lane] = acc1;
  Cz[(size_t)(m0 + 2) * c_rs + n0 + lane] = acc2;
  Cz[(size_t)(m0 + 3) * c_rs + n0 + lane] = acc3;
}

template<int KPB, int NZ, bool SILU>
__global__ __launch_bounds__(256) void k_gemv_ms(
    const float* __restrict__ A, int a_rs, int a_bs, int pz,
    const float* __restrict__ abias,
    const float* __restrict__ W, int w_rs, int w_bs,
    float* __restrict__ C, int c_rs, int c_bs, int c_zs){
  const int bb = blockIdx.y;
  gemv_ms_core<KPB, NZ, SILU>(A + (size_t)bb * a_bs, a_rs, pz, abias,
      W + (size_t)bb * w_bs, w_rs,
      C + (size_t)blockIdx.z * c_zs + (size_t)bb * c_bs, c_rs,
      blockIdx.x * 64, blockIdx.z * KPB);
}

// QKV fused: blockIdx.y selects weight matrix / output slab group (z=4).
template<int KPB>
__global__ __launch_bounds__(256) void k_gemv_ms3(
    const float* __restrict__ A, const float* __restrict__ W0,
    const float* __restrict__ W1, const float* __restrict__ W2,
    float* __restrict__ C){
  const int y = blockIdx.y;
  const float* W = (y == 0) ? W0 : ((y == 1) ? W1 : W2);
  gemv_ms_core<KPB, 0, false>(A, DIM, 0, nullptr, W, DIM,
      C + ((size_t)y * 4 + blockIdx.z) * BD, DIM,
      blockIdx.x * 64, blockIdx.z * KPB);
}

// lm_head partial combine: out[i] = P[0][i] + P[1][i]
__global__ __launch_bounds__(256) void k_fin2(const float* __restrict__ P,
                                              float* __restrict__ out){
  int i = blockIdx.x * 256 + threadIdx.x;
  out[i] = P[i] + P[(size_t)BV + i];
}

// Self-attention per (b,h). Folds the 4 QKV k-split partials (+bias),
// writes new k/v to d_out, attends over 513 keys (float4-vectorized,
// 4 rows per wave-iter, prefetched). Mask bias is softmax-invariant.
__global__ __launch_bounds__(512) void k_self_attn(
    const float* __restrict__ Pqkv, const float* __restrict__ qb_,
    const float* __restrict__ kb_, const float* __restrict__ vb_,
    const float* __restrict__ pk, const float* __restrict__ pv,
    float* __restrict__ satt, float* __restrict__ out_k,
    float* __restrict__ out_v){
  __shared__ float qs[64], ks[64], vs[64];
  __shared__ float sc[513];
  __shared__ float red1[8], red2[8];
  __shared__ float o8[8][64];
  const int bh = blockIdx.x, b = bh >> 4, h = bh & 15;
  const int tid = threadIdx.x, w = tid >> 6, lane = tid & 63;
  const int hd = h * HDIM + lane;
  if (w < 3){
    const float* Pz = Pqkv + (size_t)w * (4 * BD);
    const float* bias = (w == 0) ? qb_ : ((w == 1) ? kb_ : vb_);
    float v = bias[hd];
#pragma unroll
    for (int z = 0; z < 4; ++z)
      v += Pz[(size_t)z * BD + b * DIM + hd];
    if (w == 0) qs[lane] = v * SCALE;
    else if (w == 1){ ks[lane] = v; out_k[b * DIM + hd] = v; }
    else { vs[lane] = v; out_v[b * DIM + hd] = v; }
  }
  __syncthreads();
  const int jj = lane >> 4, c = lane & 15;
  float4 q4 = *(const float4*)(&qs[c * 4]);
  const float* kbase = pk + (size_t)b * NCACHE * DIM + h * HDIM + c * 4;
  {
    float4 nk = *(const float4*)(kbase + (size_t)(w * 4 + jj) * DIM);
    for (int it = 0; it < 16; ++it){
      int j = it * 32 + w * 4 + jj;
      float4 K4 = nk;
      if (it < 15) nk = *(const float4*)(kbase + (size_t)(j + 32) * DIM);
      float r = q4.x * K4.x;
      r = fmaf(q4.y, K4.y, r); r = fmaf(q4.z, K4.z, r); r = fmaf(q4.w, K4.w, r);
      r += __shfl_xor(r, 1, 64); r += __shfl_xor(r, 2, 64);
      r += __shfl_xor(r, 4, 64); r += __shfl_xor(r, 8, 64);
      if (c == 0) sc[j] = r;
    }
  }
  if (w == 0 && lane < 16){
    float4 k4 = *(const float4*)(&ks[lane * 4]);
    float r = q4.x * k4.x;
    r = fmaf(q4.y, k4.y, r); r = fmaf(q4.z, k4.z, r); r = fmaf(q4.w, k4.w, r);
    r += __shfl_xor(r, 1, 64); r += __shfl_xor(r, 2, 64);
    r += __shfl_xor(r, 4, 64); r += __shfl_xor(r, 8, 64);
    if (lane == 0) sc[512] = r;
  }
  __syncthreads();
  float lm = -1e30f;
  for (int j2 = tid; j2 < 513; j2 += 512) lm = fmaxf(lm, sc[j2]);
  lm = wave_reduce_max(lm);
  if (lane == 0) red1[w] = lm;
  __syncthreads();
  float bm = red1[0];
#pragma unroll
  for (int ww = 1; ww < 8; ++ww) bm = fmaxf(bm, red1[ww]);
  float ls = 0.f;
  for (int j2 = tid; j2 < 513; j2 += 512){
    float e = __expf(sc[j2] - bm);
    sc[j2] = e;
    ls += e;
  }
  ls = wave_reduce_sum(ls);
  if (lane == 0) red2[w] = ls;
  __syncthreads();
  float tot = 0.f;
#pragma unroll
  for (int ww = 0; ww < 8; ++ww) tot += red2[ww];
  float inv = 1.f / tot;
  const float* vbase = pv + (size_t)b * NCACHE * DIM + h * HDIM + c * 4;
  float4 acc; acc.x = 0.f; acc.y = 0.f; acc.z = 0.f; acc.w = 0.f;
  {
    float4 nv = *(const float4*)(vbase + (size_t)(w * 4 + jj) * DIM);
    for (int it = 0; it < 16; ++it){
      int j = it * 32 + w * 4 + jj;
      float4 V4 = nv;
      if (it < 15) nv = *(const float4*)(vbase + (size_t)(j + 32) * DIM);
      float pj = sc[j];
      acc.x = fmaf(pj, V4.x, acc.x); acc.y = fmaf(pj, V4.y, acc.y);
      acc.z = fmaf(pj, V4.z, acc.z); acc.w = fmaf(pj, V4.w, acc.w);
    }
  }
  if (w == 0 && lane < 16){
    float p512 = sc[512];
    float4 v4 = *(const float4*)(&vs[lane * 4]);
    acc.x = fmaf(p512, v4.x, acc.x); acc.y = fmaf(p512, v4.y, acc.y);
    acc.z = fmaf(p512, v4.z, acc.z); acc.w = fmaf(p512, v4.w, acc.w);
  }
  acc.x += __shfl_xor(acc.x, 16, 64); acc.x += __shfl_xor(acc.x, 32, 64);
  acc.y += __shfl_xor(acc.y, 16, 64); acc.y += __shfl_xor(acc.y, 32, 64);
  acc.z += __shfl_xor(acc.z, 16, 64); acc.z += __shfl_xor(acc.z, 32, 64);
  acc.w += __shfl_xor(acc.w, 16, 64); acc.w += __shfl_xor(acc.w, 32, 64);
  if (lane < 16){
    o8[w][lane * 4 + 0] = acc.x; o8[w][lane * 4 + 1] = acc.y;
    o8[w][lane * 4 + 2] = acc.z; o8[w][lane * 4 + 3] = acc.w;
  }
  __syncthreads();
  if (tid < 64){
    float s2 = 0.f;
#pragma unroll
    for (int ww = 0; ww < 8; ++ww) s2 += o8[ww][tid];
    satt[b * DIM + h * HDIM + tid] = s2 * inv;
  }
}

// h = LayerNorm(res + sum_z P[z] + obias) * w + b
template<int NZ>
__global__ __launch_bounds__(256) void k_add_ln_pz(
    const float* __restrict__ res, const float* __restrict__ P, int zs,
    const float* __restrict__ obias, const float* __restrict__ w,
    const float* __restrict__ bln, float* __restrict__ outh){
  __shared__ float r1[4], r2[4];
  int b = blockIdx.x, tid = threadIdx.x, wave = tid >> 6, lane = tid & 63;
  float4 rv = ((const float4*)(res + (size_t)b * DIM))[tid];
  float4 ob = ((const float4*)obias)[tid];
  float v0 = rv.x + ob.x, v1 = rv.y + ob.y, v2 = rv.z + ob.z, v3 = rv.w + ob.w;
#pragma unroll
  for (int z = 0; z < NZ; ++z){
    float4 pz = ((const float4*)(P + (size_t)z * zs + (size_t)b * DIM))[tid];
    v0 += pz.x; v1 += pz.y; v2 += pz.z; v3 += pz.w;
  }
  float s = v0 + v1 + v2 + v3;
  float sq = v0 * v0 + v1 * v1 + v2 * v2 + v3 * v3;
  s = wave_reduce_sum(s); sq = wave_reduce_sum(sq);
  if (lane == 0){ r1[wave] = s; r2[wave] = sq; }
  __syncthreads();
  float ts = r1[0] + r1[1] + r1[2] + r1[3];
  float tq = r2[0] + r2[1] + r2[2] + r2[3];
  float mean = ts * (1.f / DIM);
  float var = tq * (1.f / DIM) - mean * mean;
  float rstd = rsqrtf(var + 1e-5f);
  float4 wv = ((const float4*)w)[tid], bv = ((const float4*)bln)[tid];
  float4 o;
  o.x = (v0 - mean) * rstd * wv.x + bv.x;
  o.y = (v1 - mean) * rstd * wv.y + bv.y;
  o.z = (v2 - mean) * rstd * wv.z + bv.z;
  o.w = (v3 - mean) * rstd * wv.w + bv.w;
  ((float4*)(outh + (size_t)b * DIM))[tid] = o;
}

// g[b][h][c] = sum_d qv[b][hd] * kw[hd][c], qv = (sum8 Pcq + caqb)*SCALE
__global__ __launch_bounds__(256) void k_gmat2(
    const float* __restrict__ Pcq, const float* __restrict__ caqb,
    const float* __restrict__ kw, float* __restrict__ g){
  __shared__ float qsT[64][16];   // [d][b]
  __shared__ float Ps[4][16][64];
  const int h = blockIdx.y, c0 = blockIdx.x * 64;
  const int tid = threadIdx.x, lane = tid & 63, wave = tid >> 6;
  {
    const int b = tid >> 4, q0 = (tid & 15) * 4;
    float4 v = *(const float4*)(caqb + h * HDIM + q0);
#pragma unroll
    for (int z = 0; z < 8; ++z){
      float4 pv = *(const float4*)(Pcq + (size_t)z * BD +
                                   (size_t)b * DIM + h * HDIM + q0);
      v.x += pv.x; v.y += pv.y; v.z += pv.z; v.w += pv.w;
    }
    qsT[q0 + 0][b] = v.x * SCALE; qsT[q0 + 1][b] = v.y * SCALE;
    qsT[q0 + 2][b] = v.z * SCALE; qsT[q0 + 3][b] = v.w * SCALE;
  }
  __syncthreads();
  float wv[16];
#pragma unroll
  for (int dd = 0; dd < 16; ++dd)
    wv[dd] = kw[(size_t)(h * HDIM + wave * 16 + dd) * DIM + c0 + lane];
  float acc[16];
#pragma unroll
  for (int m = 0; m < 16; ++m) acc[m] = 0.f;
#pragma unroll
  for (int dd = 0; dd < 16; ++dd){
    const int d = wave * 16 + dd;
    float4 a0 = *(const float4*)(&qsT[d][0]);
    float4 a1 = *(const float4*)(&qsT[d][4]);
    float4 a2 = *(const float4*)(&qsT[d][8]);
    float4 a3 = *(const float4*)(&qsT[d][12]);
    float wd = wv[dd];
    acc[0] = fmaf(wd, a0.x, acc[0]);  acc[1] = fmaf(wd, a0.y, acc[1]);
    acc[2] = fmaf(wd, a0.z, acc[2]);  acc[3] = fmaf(wd, a0.w, acc[3]);
    acc[4] = fmaf(wd, a1.x, acc[4]);  acc[5] = fmaf(wd, a1.y, acc[5]);
    acc[6] = fmaf(wd, a1.z, acc[6]);  acc[7] = fmaf(wd, a1.w, acc[7]);
    acc[8] = fmaf(wd, a2.x, acc[8]);  acc[9] = fmaf(wd, a2.y, acc[9]);
    acc[10] = fmaf(wd, a2.z, acc[10]); acc[11] = fmaf(wd, a2.w, acc[11]);
    acc[12] = fmaf(wd, a3.x, acc[12]); acc[13] = fmaf(wd, a3.y, acc[13]);
    acc[14] = fmaf(wd, a3.z, acc[14]); acc[15] = fmaf(wd, a3.w, acc[15]);
  }
#pragma unroll
  for (int m = 0; m < 16; ++m) Ps[wave][m][lane] = acc[m];
  __syncthreads();
  const int nl = tid & 63, mg = (tid >> 6) * 4;
#pragma unroll
  for (int mm = 0; mm < 4; ++mm){
    int m = mg + mm;
    float r = Ps[0][m][nl] + Ps[1][m][nl] + Ps[2][m][nl] + Ps[3][m][nl];
    g[((size_t)m * NH + h) * DIM + c0 + nl] = r;
  }
}

// ctx with INLINE softmax: stages p = softmax(sum of 2 score slabs) into
// LDS transposed, then ctx[b][h][c] = sum_j p[b][h][j]*enc[b][j][c].
// grid: (16 c-tiles, 16 b)
__global__ __launch_bounds__(256) void k_ctx_sm(
    const float* __restrict__ s2b, const float* __restrict__ enc,
    float* __restrict__ ctx){
  __shared__ float pT[SRCLEN][16];
  __shared__ float Ps[4][16][64];
  const int b = blockIdx.y, c0 = blockIdx.x * 64;
  const int tid = threadIdx.x, lane = tid & 63, wave = tid >> 6;
  {
    const int h = tid >> 4, jp = (tid & 15) * 4;
    const size_t row = ((size_t)b * NH + h) * SRCLEN;
    float4 val[8];
    float vmax = -1e30f;
#pragma unroll
    for (int t = 0; t < 8; ++t){
      const int j = jp + t * 64;
      float4 v = *(const float4*)(s2b + row + j);
      float4 v2 = *(const float4*)(s2b + (size_t)(BATCH * NH * SRCLEN) + row + j);
      v.x += v2.x; v.y += v2.y; v.z += v2.z; v.w += v2.w;
      val[t] = v;
      vmax = fmaxf(vmax, fmaxf(fmaxf(v.x, v.y), fmaxf(v.z, v.w)));
    }
#pragma unroll
    for (int o = 1; o <= 8; o <<= 1) vmax = fmaxf(vmax, __shfl_xor(vmax, o, 64));
    float lsum = 0.f;
#pragma unroll
    for (int t = 0; t < 8; ++t){
      val[t].x = __expf(val[t].x - vmax); val[t].y = __expf(val[t].y - vmax);
      val[t].z = __expf(val[t].z - vmax); val[t].w = __expf(val[t].w - vmax);
      lsum += val[t].x + val[t].y + val[t].z + val[t].w;
    }
#pragma unroll
    for (int o = 1; o <= 8; o <<= 1) lsum += __shfl_xor(lsum, o, 64);
    float inv = 1.f / lsum;
#pragma unroll
    for (int t = 0; t < 8; ++t){
      const int j = jp + t * 64;
      pT[j + 0][h] = val[t].x * inv; pT[j + 1][h] = val[t].y * inv;
      pT[j + 2][h] = val[t].z * inv; pT[j + 3][h] = val[t].w * inv;
    }
  }
  __syncthreads();
  const float* ep = enc + (size_t)b * SRCLEN * DIM + c0 + lane;
  const int jb = wave * 128;
  float acc[16];
#pragma unroll
  for (int m = 0; m < 16; ++m) acc[m] = 0.f;
  float cur[8], nxt[8];
#pragma unroll
  for (int i = 0; i < 8; ++i) cur[i] = ep[(size_t)(jb + i) * DIM];
#pragma unroll
  for (int t = 0; t < 16; ++t){
    if (t < 15){
#pragma unroll
      for (int i = 0; i < 8; ++i)
        nxt[i] = ep[(size_t)(jb + (t + 1) * 8 + i) * DIM];
    }
#pragma unroll
    for (int i = 0; i < 8; ++i){
      const int j = jb + t * 8 + i;
      float4 p0 = *(const float4*)(&pT[j][0]);
      float4 p1 = *(const float4*)(&pT[j][4]);
      float4 p2 = *(const float4*)(&pT[j][8]);
      float4 p3 = *(const float4*)(&pT[j][12]);
      float ev = cur[i];
      acc[0] = fmaf(p0.x, ev, acc[0]);  acc[1] = fmaf(p0.y, ev, acc[1]);
      acc[2] = fmaf(p0.z, ev, acc[2]);  acc[3] = fmaf(p0.w, ev, acc[3]);
      acc[4] = fmaf(p1.x, ev, acc[4]);  acc[5] = fmaf(p1.y, ev, acc[5]);
      acc[6] = fmaf(p1.z, ev, acc[6]);  acc[7] = fmaf(p1.w, ev, acc[7]);
      acc[8] = fmaf(p2.x, ev, acc[8]);  acc[9] = fmaf(p2.y, ev, acc[9]);
      acc[10] = fmaf(p2.z, ev, acc[10]); acc[11] = fmaf(p2.w, ev, acc[11]);
      acc[12] = fmaf(p3.x, ev, acc[12]); acc[13] = fmaf(p3.y, ev, acc[13]);
      acc[14] = fmaf(p3.z, ev, acc[14]); acc[15] = fmaf(p3.w, ev, acc[15]);
    }
#pragma unroll
    for (int i = 0; i < 8; ++i) cur[i] = nxt[i];
  }
#pragma unroll
  for (int m = 0; m < 16; ++m) Ps[wave][m][lane] = acc[m];
  __syncthreads();
  const int nl = tid & 63, mg = (tid >> 6) * 4;
#pragma unroll
  for (int mm = 0; mm < 4; ++mm){
    int m = mg + mm;
    float r = Ps[0][m][nl] + Ps[1][m][nl] + Ps[2][m][nl] + Ps[3][m][nl];
    ctx[((size_t)b * NH + m) * DIM + c0 + nl] = r;
  }
}

extern "C" void kernel_launch(void* const* d_in, const int* in_sizes, int n_in,
                              void* d_out, int out_size, void* d_ws, size_t ws_size,
                              hipStream_t stream){
  const float* de   = (const float*)d_in[0];
  const float* enc  = (const float*)d_in[1];
  const float* pk   = (const float*)d_in[2];
  const float* pv   = (const float*)d_in[3];
  const int*   cl   = (const int*)d_in[4];
  const float* pe   = (const float*)d_in[5];
  const float* saqw = (const float*)d_in[6];
  const float* sakw = (const float*)d_in[7];
  const float* savw = (const float*)d_in[8];
  const float* saow = (const float*)d_in[9];
  const float* caqw = (const float*)d_in[10];
  const float* cakw = (const float*)d_in[11];
  const float* cavw = (const float*)d_in[12];
  const float* caow = (const float*)d_in[13];
  const float* saqb = (const float*)d_in[14];
  const float* sakb = (const float*)d_in[15];
  const float* savb = (const float*)d_in[16];
  const float* saob = (const float*)d_in[17];
  const float* caqb = (const float*)d_in[18];
  const float* cakb = (const float*)d_in[19];
  const float* cavb = (const float*)d_in[20];
  const float* caob = (const float*)d_in[21];
  const float* fc1w = (const float*)d_in[22];
  const float* fc1b = (const float*)d_in[23];
  const float* fc2w = (const float*)d_in[24];
  const float* fc2b = (const float*)d_in[25];
  const float* ln1w = (const float*)d_in[26];
  const float* ln2w = (const float*)d_in[27];
  const float* ln3w = (const float*)d_in[28];
  const float* ln1b = (const float*)d_in[29];
  const float* ln2b = (const float*)d_in[30];
  const float* ln3b = (const float*)d_in[31];
  const float* lmw  = (const float*)d_in[32];
  float* out = (float*)d_out;
  float* ws  = (float*)d_ws;

  float* h    = ws;              // [16][1024]
  float* satt = ws + 16384;      // [16][1024]
  float* g    = ws + 32768;      // [16][16][1024]
  float* ctx  = ws + 294912;     // [16][16][1024]
  float* Pqkv = ws + 557056;     // [3][4][16][1024]
  float* Po   = ws + 950272;     // [8][16][1024]
  float* Pcq  = ws + 1212416;    // [8][16][1024]
  float* Pvo  = ws + 1474560;    // [8][16][1024]
  float* Pco  = ws + 1736704;    // [8][16][1024]
  float* Pf1  = ws + 1998848;    // [4][16][4096]
  float* Pf2  = ws + 2523136;    // [32][16][1024]
  float* s2b  = ws + 3047424;    // [2][256][512]
  float* Plm  = ws + 4096000;    // [2][16][32000]

  float* out_k = out + 512000;   // [L][16][1024]
  float* out_v = out + 610304;   // [L][16][1024]

  k_embed<<<16, 256, 0, stream>>>(de, pe, cl, h);

  for (int i = 0; i < LYRS; ++i){
    size_t wo = (size_t)i * DIM * DIM;
    size_t bo = (size_t)i * DIM;
    float* ko = out_k + (size_t)i * BD;
    float* vo = out_v + (size_t)i * BD;
    // ---- self-attention ----
    k_gemv_ms3<256><<<dim3(16, 3, 4), 256, 0, stream>>>(h, saqw + wo, sakw + wo,
        savw + wo, Pqkv);
    k_self_attn<<<256, 512, 0, stream>>>(Pqkv, saqb + bo, sakb + bo, savb + bo,
        pk + (size_t)i * BATCH * NCACHE * DIM, pv + (size_t)i * BATCH * NCACHE * DIM,
        satt, ko, vo);
    k_gemv_ms<128, 0, false><<<dim3(16, 1, 8), 256, 0, stream>>>(satt, DIM, 0, 0,
        nullptr, saow + wo, DIM, 0, Po, DIM, 0, BD);
    k_add_ln_pz<8><<<16, 256, 0, stream>>>(h, Po, BD, saob + bo,
        ln1w + bo, ln1b + bo, h);
    // ---- cross-attention (K/V projections folded around the softmax) ----
    k_gemv_ms<128, 0, false><<<dim3(16, 1, 8), 256, 0, stream>>>(h, DIM, 0, 0,
        nullptr, caqw + wo, DIM, 0, Pcq, DIM, 0, BD);
    k_gmat2<<<dim3(16, 16), 256, 0, stream>>>(Pcq, caqb + bo, cakw + wo, g);
    k_gemv_ms<512, 0, false><<<dim3(8, 16, 2), 256, 0, stream>>>(g, DIM, NH * DIM,
        0, nullptr, enc, DIM, SRCLEN * DIM, s2b, SRCLEN, NH * SRCLEN,
        BATCH * NH * SRCLEN);
    k_ctx_sm<<<dim3(16, 16), 256, 0, stream>>>(s2b, enc, ctx);
    k_gemv_ms<128, 0, false><<<dim3(1, 16, 8), 256, 0, stream>>>(ctx, NH * DIM,
        DIM, 0, nullptr, cavw + wo, DIM, HDIM * DIM, Pvo, DIM, HDIM, BD);
    k_gemv_ms<128, 8, false><<<dim3(16, 1, 8), 256, 0, stream>>>(Pvo, DIM, 0,
        BD, cavb + bo, caow + wo, DIM, 0, Pco, DIM, 0, BD);
    k_add_ln_pz<8><<<16, 256, 0, stream>>>(h, Pco, BD, caob + bo,
        ln2w + bo, ln2b + bo, h);
    // ---- FFN ----
    k_gemv_ms<256, 0, false><<<dim3(64, 1, 4), 256, 0, stream>>>(h, DIM, 0, 0,
        nullptr, fc1w + (size_t)i * FFNDIM * DIM, DIM, 0, Pf1, FFNDIM, 0, BF);
    k_gemv_ms<128, 4, true><<<dim3(16, 1, 32), 256, 0, stream>>>(Pf1, FFNDIM, 0,
        BF, fc1b + (size_t)i * FFNDIM,
        fc2w + (size_t)i * DIM * FFNDIM, FFNDIM, 0, Pf2, DIM, 0, BD);
    k_add_ln_pz<32><<<16, 256, 0, stream>>>(h, Pf2, BD, fc2b + bo,
        ln3w + bo, ln3b + bo, h);
  }
  // ---- lm_head ----
  k_gemv_ms<512, 0, false><<<dim3(VOCAB / 64, 1, 2), 256, 0, stream>>>(h, DIM, 0,
      0, nullptr, lmw, DIM, 0, Plm, VOCAB, 0, BV);
  k_fin2<<<BV / 256, 256, 0, stream>>>(Plm, out);
}